// Round 8
// baseline (375.633 us; speedup 1.0000x reference)
//
#include <hip/hip_runtime.h>
#include <hip/hip_bf16.h>

// HMM count-accumulation with NO scattered global writes.
// out = [trans_count 65*65=4225 | emit_count 500000*64=32M] floats.
//
// Ladder: R1/R2 scattered global atomics wall (~30G txn/s, occupancy-blind);
// R5 scattered u16 stores hit the same wall; R6 counting-sort removes both;
// R7 wave-shuffle scan (-12us). R8: phase1 1 tile/block @ 512 thr (shorter
// barrier drains, 3 blk/CU), transpose kernel dropped (phase2 reads dir
// column-strided, L2-resident), phase2 LDS zero vectorized.

constexpr int N_WORDS  = 500000;
constexpr int N_LABELS = 64;
constexpr int SEQ_LEN  = 512;
constexpr int BINS     = (N_LABELS + 1) * (N_LABELS + 1);   // 4225
constexpr int N_CELLS  = N_WORDS * N_LABELS;                // 32,000,000
constexpr int P        = 1000;     // emit partitions; P*CPP == N_CELLS exactly
constexpr int CPP      = 32000;    // cells/partition; u16 counts = 64,000 B LDS
constexpr int TILE_TOK = 4096;     // tokens per phase-1 tile
constexpr int QPT      = TILE_TOK / 4;   // 1024 quads/tile
constexpr int B1 = 512;            // 8 waves
constexpr int MAXT = 1024;         // max tiles a launch supports via part_t rows
constexpr int B2 = 1024;
constexpr int FIN_BLOCKS = 5;      // 5*1024 >= 4225

// ---------------- phase 1: tile counting sort + trans hist ----------------

__global__ __launch_bounds__(B1)
void phase1(const int* __restrict__ words, const int* __restrict__ labels,
            unsigned* __restrict__ dir,            // [ntiles][P]  (cnt<<16)|off
            unsigned short* __restrict__ keys,     // [ntiles][TILE_TOK] sorted loc
            unsigned* __restrict__ part_t,         // [gridDim][BINS] trans partials
            int n, int ntiles) {
    __shared__ unsigned trans[BINS];               // 16.9 KB
    __shared__ unsigned keybuf[TILE_TOK];          // 16 KB  (p<<16)|loc, ~0u = pad
    __shared__ unsigned short sorted[TILE_TOK];    // 8 KB
    __shared__ unsigned cnt[1024];                 // 4 KB; reused as scatter cursor
    __shared__ unsigned wsum[8];
    const int tid  = threadIdx.x;
    const int lane = tid & 63;
    const int wid  = tid >> 6;
    for (int k = tid; k < BINS; k += B1) trans[k] = 0u;

    const int nquads = n >> 2;
    for (int tile = blockIdx.x; tile < ntiles; tile += gridDim.x) {
        const int q0 = tile * QPT;
        const int tq = min(QPT, nquads - q0);
        cnt[tid] = 0u; cnt[tid + 512] = 0u;
        __syncthreads();

        // pass A: two quads per thread; keys -> LDS, partition counts, trans hist
        for (int lq = tid; lq < tq; lq += B1) {
            const int q = q0 + lq;
            const int i = q << 2;
            const int4 w4 = reinterpret_cast<const int4*>(words)[q];
            const int4 l4 = reinterpret_cast<const int4*>(labels)[q];
            const int j0 = i & (SEQ_LEN - 1);
            int pre = (j0 == 0) ? N_LABELS : labels[i - 1];
            int wv[4] = {w4.x, w4.y, w4.z, w4.w};
            int lv[4] = {l4.x, l4.y, l4.z, l4.w};
            unsigned pk[4];
            #pragma unroll
            for (int k = 0; k < 4; ++k) {
                const int lab = lv[k];
                unsigned pack = 0xFFFFFFFFu;
                if (wv[k] != 0) {
                    atomicAdd(&trans[lab * (N_LABELS + 1) + pre], 1u);
                    const int w = (wv[k] >= N_WORDS) ? 1 : wv[k];
                    const unsigned key = (unsigned)w * N_LABELS + (unsigned)lab;
                    const unsigned p   = key / CPP;        // magic-mul const div
                    pack = (p << 16) | (key - p * CPP);    // loc < 32000 fits u16
                    atomicAdd(&cnt[p], 1u);
                }
                pk[k] = pack;
                pre = lab;
            }
            reinterpret_cast<uint4*>(keybuf)[lq] = make_uint4(pk[0], pk[1], pk[2], pk[3]);
        }
        __syncthreads();

        // pair-wise hierarchical scan of cnt[1024] with 512 threads, 2 barriers
        {
            const unsigned c0 = cnt[2 * tid], c1 = cnt[2 * tid + 1];
            const unsigned s  = c0 + c1;
            unsigned v = s;
            #pragma unroll
            for (int d = 1; d < 64; d <<= 1) {
                const unsigned u = __shfl_up(v, d, 64);
                if (lane >= d) v += u;
            }
            if (lane == 63) wsum[wid] = v;
            __syncthreads();
            if (tid < 8) {
                const unsigned sv = wsum[tid];
                unsigned vv = sv;
                #pragma unroll
                for (int d = 1; d < 8; d <<= 1) {
                    const unsigned u = __shfl_up(vv, d, 64);
                    if (tid >= d) vv += u;
                }
                wsum[tid] = vv - sv;               // exclusive wave prefix
            }
            __syncthreads();
            const unsigned ex = v - s + wsum[wid]; // exclusive offset of cell 2*tid
            cnt[2 * tid]     = ex;                 // reuse as scatter cursor
            cnt[2 * tid + 1] = ex + c0;
            if (2 * tid + 1 < P)                   // threads 0..499: uint2 dir write
                reinterpret_cast<uint2*>(dir + (size_t)tile * P)[tid] =
                    make_uint2((c0 << 16) | ex, (c1 << 16) | (ex + c0));
        }
        __syncthreads();

        // pass B: LDS scatter into sorted order
        const int tt = tq << 2;
        for (int t = tid; t < tt; t += B1) {
            const unsigned pack = keybuf[t];
            if (pack != 0xFFFFFFFFu) {
                const unsigned s = atomicAdd(&cnt[pack >> 16], 1u);
                sorted[s] = (unsigned short)(pack & 0xFFFFu);
            }
        }
        __syncthreads();

        // coalesced write of the sorted tile (8 KB contiguous; garbage tail ok)
        reinterpret_cast<uint4*>(keys + (size_t)tile * TILE_TOK)[tid] =
            reinterpret_cast<const uint4*>(sorted)[tid];
        __syncthreads();
    }

    unsigned* my = part_t + (size_t)blockIdx.x * BINS;
    for (int k = tid; k < BINS; k += B1) my[k] = trans[k];  // plain coalesced
}

// ---------------- phase 2: emit slices + fused trans finalize ----------------

__global__ __launch_bounds__(B2)
void phase2(const unsigned* __restrict__ dir,              // [ntiles][P]
            const unsigned short* __restrict__ keys,       // [ntiles][TILE_TOK]
            const unsigned* __restrict__ part_t,
            float* __restrict__ out, int ntiles, int g1) {
    extern __shared__ unsigned h[];                        // 16,000 u32 packed u16
    const unsigned bid = blockIdx.x;

    if (bid < (unsigned)FIN_BLOCKS) {                      // fused trans finalize
        const int k = bid * B2 + threadIdx.x;              // first scheduling round,
        if (k < BINS) {                                    // hides under emit blocks
            unsigned s = 0;
            for (int pb = 0; pb < g1; ++pb) s += part_t[(size_t)pb * BINS + k];
            out[k] = (float)s;
        }
        return;
    }
    const unsigned p = bid - FIN_BLOCKS;                   // partition index

    for (int j = threadIdx.x; j < CPP / 8; j += B2)        // 64KB zero, b128
        reinterpret_cast<uint4*>(h)[j] = make_uint4(0u, 0u, 0u, 0u);
    __syncthreads();

    // column-strided dir reads (stride 4000B, L2-resident, p-adjacent blocks share lines)
    for (int t = threadIdx.x; t < ntiles; t += B2) {
        const unsigned e = dir[(size_t)t * P + p];
        unsigned c = e >> 16;
        const unsigned short* kp = keys + (size_t)t * TILE_TOK + (e & 0xFFFFu);
        for (unsigned i = 0; i < c; ++i) {
            const unsigned loc = kp[i];
            atomicAdd(&h[loc >> 1], (loc & 1u) ? 65536u : 1u);
        }
    }
    __syncthreads();

    // write sweep; emit + p*CPP is ==4 (mod 16) aligned (proven exact R5-R7)
    float* __restrict__ emit = out + BINS;
    float* dst = emit + (size_t)p * CPP;
    if (threadIdx.x < 3)
        dst[threadIdx.x] =
            (float)((h[threadIdx.x >> 1] >> ((threadIdx.x & 1u) * 16)) & 0xFFFFu);
    if (threadIdx.x == 3)
        dst[CPP - 1] = (float)(h[(CPP - 1) >> 1] >> 16);
    float4* dst4 = reinterpret_cast<float4*>(dst + 3);
    for (int u = threadIdx.x; u < (CPP - 4) / 4; u += B2) {   // 7999 float4s
        const unsigned w0 = h[2 * u + 1];
        const unsigned w1 = h[2 * u + 2];
        const unsigned w2 = h[2 * u + 3];
        float4 f;
        f.x = (float)(w0 >> 16);
        f.y = (float)(w1 & 0xFFFFu);
        f.z = (float)(w1 >> 16);
        f.w = (float)(w2 & 0xFFFFu);
        dst4[u] = f;
    }
}

// ---------------- fallback (ws too small) ----------------

__global__ __launch_bounds__(256)
void zero_kernel(uint4* __restrict__ out, int out_quads, int out_size) {
    const uint4 z = {0u, 0u, 0u, 0u};
    const int stride = gridDim.x * blockDim.x;
    for (int q = blockIdx.x * blockDim.x + threadIdx.x; q < out_quads; q += stride)
        out[q] = z;
    if (blockIdx.x == 0 && threadIdx.x < (out_size & 3))
        ((unsigned*)out)[(out_quads << 2) + threadIdx.x] = 0u;
}

__global__ __launch_bounds__(1024)
void count_fallback(const int* __restrict__ words, const int* __restrict__ labels,
                    float* __restrict__ out, int nquads) {
    __shared__ unsigned hist[BINS];
    for (int k = threadIdx.x; k < BINS; k += 1024) hist[k] = 0u;
    __syncthreads();
    float* __restrict__ emit = out + BINS;
    const int stride = gridDim.x * blockDim.x;
    for (int q = blockIdx.x * blockDim.x + threadIdx.x; q < nquads; q += stride) {
        const int i = q << 2;
        const int4 w4 = reinterpret_cast<const int4*>(words)[q];
        const int4 l4 = reinterpret_cast<const int4*>(labels)[q];
        const int j0 = i & (SEQ_LEN - 1);
        int pre = (j0 == 0) ? N_LABELS : labels[i - 1];
        int wv[4] = {w4.x, w4.y, w4.z, w4.w};
        int lv[4] = {l4.x, l4.y, l4.z, l4.w};
        #pragma unroll
        for (int k = 0; k < 4; ++k) {
            const int w = wv[k], lab = lv[k];
            if (w != 0) {
                atomicAdd(&hist[lab * (N_LABELS + 1) + pre], 1u);
                const int we = (w >= N_WORDS) ? 1 : w;
                atomicAdd(&emit[(size_t)we * N_LABELS + lab], 1.0f);
            }
            pre = lab;
        }
    }
    __syncthreads();
    for (int k = threadIdx.x; k < BINS; k += 1024) {
        const unsigned c = hist[k];
        if (c) atomicAdd(&out[k], (float)c);
    }
}

// ---------------- launch ----------------

extern "C" void kernel_launch(void* const* d_in, const int* in_sizes, int n_in,
                              void* d_out, int out_size, void* d_ws, size_t ws_size,
                              hipStream_t stream) {
    const int* words  = (const int*)d_in[0];
    const int* labels = (const int*)d_in[1];
    float* out = (float*)d_out;
    const int n = in_sizes[0];

    const int nquads = n >> 2;
    const int ntiles = (nquads + QPT - 1) / QPT;            // 1024 at full size
    const int g1     = ntiles < MAXT ? ntiles : MAXT;       // phase1 grid

    // ws: dir | keys | part_t
    const size_t dir_bytes  = (size_t)ntiles * P * sizeof(unsigned);
    const size_t key_bytes  = (size_t)ntiles * TILE_TOK * sizeof(unsigned short);
    const size_t part_bytes = (size_t)g1 * BINS * sizeof(unsigned);
    const size_t dir_off  = 0;
    const size_t key_off  = dir_off + ((dir_bytes + 255) & ~size_t(255));
    const size_t part_off = key_off + ((key_bytes + 255) & ~size_t(255));
    const size_t need     = part_off + part_bytes;

    if (ws_size >= need) {
        unsigned*       dir    = (unsigned*)((char*)d_ws + dir_off);
        unsigned short* keys   = (unsigned short*)((char*)d_ws + key_off);
        unsigned*       part_t = (unsigned*)((char*)d_ws + part_off);

        phase1<<<g1, B1, 0, stream>>>(words, labels, dir, keys, part_t, n, ntiles);
        phase2<<<P + FIN_BLOCKS, B2, (CPP / 2) * sizeof(unsigned), stream>>>(
            dir, keys, part_t, out, ntiles, g1);
    } else {
        const int out_quads = out_size >> 2;
        zero_kernel<<<2048, 256, 0, stream>>>((uint4*)d_out, out_quads, out_size);
        count_fallback<<<512, 1024, 0, stream>>>(words, labels, out, nquads);
    }
}

// Round 9
// 254.251 us; speedup vs baseline: 1.4774x; 1.4774x over previous
//
#include <hip/hip_runtime.h>
#include <hip/hip_bf16.h>

// HMM count-accumulation with NO scattered global writes.
// out = [trans_count 65*65=4225 | emit_count 500000*64=32M] floats.
//
// Ladder: R1/R2 scattered global atomics wall (~30G txn/s, occupancy-blind);
// R5 scattered u16 stores same wall; R6 counting-sort removes both; R7
// wave-shuffle scan (254.5us, best); R8 dropped the dir transpose -> phase2
// column reads cost +100us (FETCH 24->51MB) -- REVERTED. R9: TILE 8192
// (half the segments, half the phase1 scans), 2 threads/segment in phase2.

constexpr int N_WORDS  = 500000;
constexpr int N_LABELS = 64;
constexpr int SEQ_LEN  = 512;
constexpr int BINS     = (N_LABELS + 1) * (N_LABELS + 1);   // 4225
constexpr int N_CELLS  = N_WORDS * N_LABELS;                // 32,000,000
constexpr int P        = 1000;     // emit partitions; P*CPP == N_CELLS exactly
constexpr int CPP      = 32000;    // cells/partition; u16 counts = 64,000 B LDS
constexpr int TILE_TOK = 8192;     // tokens per phase-1 tile
constexpr int QPT      = TILE_TOK / 4;   // 2048 quads/tile
constexpr int B1 = 1024, G1 = 512;
constexpr int B2 = 1024;
constexpr int FIN_BLOCKS = 5;      // 5*1024 >= 4225

// ---------------- phase 1: tile counting sort + trans hist ----------------

__global__ __launch_bounds__(B1)
void phase1(const int* __restrict__ words, const int* __restrict__ labels,
            unsigned* __restrict__ dir,            // [ntiles][P]  (cnt<<16)|off
            unsigned short* __restrict__ keys,     // [ntiles][TILE_TOK] sorted loc
            unsigned* __restrict__ part_t,         // [G1][BINS] trans partials
            int n, int ntiles) {
    __shared__ unsigned trans[BINS];               // 16.9 KB
    __shared__ unsigned keybuf[TILE_TOK];          // 32 KB  (p<<16)|loc, ~0u = pad
    __shared__ unsigned short sorted[TILE_TOK];    // 16 KB
    __shared__ unsigned cnt[1024];                 // 4 KB; reused as scatter cursor
    __shared__ unsigned wsum[16];
    const int tid  = threadIdx.x;
    const int lane = tid & 63;
    for (int k = tid; k < BINS; k += B1) trans[k] = 0u;

    const int nquads = n >> 2;
    for (int tile = blockIdx.x; tile < ntiles; tile += gridDim.x) {
        const int q0 = tile * QPT;
        const int tq = min(QPT, nquads - q0);
        cnt[tid] = 0u;
        __syncthreads();

        // pass A: two quads per thread; keys -> LDS, partition counts, trans hist
        for (int lq = tid; lq < tq; lq += B1) {
            const int q = q0 + lq;
            const int i = q << 2;
            const int4 w4 = reinterpret_cast<const int4*>(words)[q];
            const int4 l4 = reinterpret_cast<const int4*>(labels)[q];
            const int j0 = i & (SEQ_LEN - 1);
            int pre = (j0 == 0) ? N_LABELS : labels[i - 1];
            int wv[4] = {w4.x, w4.y, w4.z, w4.w};
            int lv[4] = {l4.x, l4.y, l4.z, l4.w};
            unsigned pk[4];
            #pragma unroll
            for (int k = 0; k < 4; ++k) {
                const int lab = lv[k];
                unsigned pack = 0xFFFFFFFFu;
                if (wv[k] != 0) {
                    atomicAdd(&trans[lab * (N_LABELS + 1) + pre], 1u);
                    const int w = (wv[k] >= N_WORDS) ? 1 : wv[k];
                    const unsigned key = (unsigned)w * N_LABELS + (unsigned)lab;
                    const unsigned p   = key / CPP;        // magic-mul const div
                    pack = (p << 16) | (key - p * CPP);    // loc < 32000 fits u16
                    atomicAdd(&cnt[p], 1u);
                }
                pk[k] = pack;
                pre = lab;
            }
            reinterpret_cast<uint4*>(keybuf)[lq] = make_uint4(pk[0], pk[1], pk[2], pk[3]);
        }
        __syncthreads();

        // hierarchical scan of cnt[1024]: wave shfl scan + wave-sum scan, 2 barriers
        {
            const unsigned c = cnt[tid];
            unsigned v = c;
            #pragma unroll
            for (int d = 1; d < 64; d <<= 1) {
                const unsigned u = __shfl_up(v, d, 64);
                if (lane >= d) v += u;
            }
            if (lane == 63) wsum[tid >> 6] = v;
            __syncthreads();
            if (tid < 16) {
                const unsigned s = wsum[tid];
                unsigned vv = s;
                #pragma unroll
                for (int d = 1; d < 16; d <<= 1) {
                    const unsigned u = __shfl_up(vv, d, 64);
                    if (tid >= d) vv += u;
                }
                wsum[tid] = vv - s;                 // exclusive wave prefix
            }
            __syncthreads();
            const unsigned off = v - c + wsum[tid >> 6];  // exclusive offset
            cnt[tid] = off;                                // reuse as cursor
            if (tid < P) dir[(size_t)tile * P + tid] = (c << 16) | off;  // coalesced
        }
        __syncthreads();

        // pass B: LDS scatter into sorted order
        const int tt = tq << 2;
        for (int t = tid; t < tt; t += B1) {
            const unsigned pack = keybuf[t];
            if (pack != 0xFFFFFFFFu) {
                const unsigned s = atomicAdd(&cnt[pack >> 16], 1u);
                sorted[s] = (unsigned short)(pack & 0xFFFFu);
            }
        }
        __syncthreads();

        // coalesced write of the sorted tile (16 KB contiguous; garbage tail ok)
        reinterpret_cast<uint4*>(keys + (size_t)tile * TILE_TOK)[tid] =
            reinterpret_cast<const uint4*>(sorted)[tid];
        __syncthreads();
    }

    unsigned* my = part_t + (size_t)blockIdx.x * BINS;
    for (int k = tid; k < BINS; k += B1) my[k] = trans[k];  // plain coalesced
}

// ---------------- directory transpose: dir[t][p] -> dirT[p][t] ----------------

__global__ __launch_bounds__(256)
void transpose_dir(const unsigned* __restrict__ dir, unsigned* __restrict__ dirT,
                   int ntiles, int tstride) {
    __shared__ unsigned tb[32][33];
    const int p0 = blockIdx.x * 32, t0 = blockIdx.y * 32;
    const int tx = threadIdx.x, ty = threadIdx.y;          // block (32,8)
    for (int j = ty; j < 32; j += 8) {
        const int t = t0 + j, p = p0 + tx;
        tb[j][tx] = (t < ntiles && p < P) ? dir[(size_t)t * P + p] : 0u;
    }
    __syncthreads();
    for (int j = ty; j < 32; j += 8) {
        const int p = p0 + j, t = t0 + tx;
        if (p < P && t < tstride) dirT[(size_t)p * tstride + t] = tb[tx][j];
    }
}

// ---------------- phase 2: emit slices + fused trans finalize ----------------

__global__ __launch_bounds__(B2)
void phase2(const unsigned* __restrict__ dirT,             // [P][tstride]
            const unsigned short* __restrict__ keys,       // [ntiles][TILE_TOK]
            const unsigned* __restrict__ part_t,
            float* __restrict__ out, int ntiles, int tstride) {
    extern __shared__ unsigned h[];                        // 16,000 u32 packed u16
    const unsigned bid = blockIdx.x;

    if (bid < (unsigned)FIN_BLOCKS) {                      // fused trans finalize
        const int k = bid * B2 + threadIdx.x;              // first scheduling round,
        if (k < BINS) {                                    // hides under emit blocks
            unsigned s = 0;
            #pragma unroll 8
            for (int pb = 0; pb < G1; ++pb) s += part_t[(size_t)pb * BINS + k];
            out[k] = (float)s;
        }
        return;
    }
    const unsigned p = bid - FIN_BLOCKS;                   // partition index

    for (int j = threadIdx.x; j < CPP / 8; j += B2)        // 64KB zero, b128
        reinterpret_cast<uint4*>(h)[j] = make_uint4(0u, 0u, 0u, 0u);
    __syncthreads();

    // coalesced dirT row; TWO threads per segment halve the serial key chain
    const unsigned* drow = dirT + (size_t)p * tstride;
    const int nseg = ntiles << 1;
    for (int s = threadIdx.x; s < nseg; s += B2) {
        const int t = s >> 1, half = s & 1;
        const unsigned e = drow[t];                        // pair reads same entry
        const unsigned c = e >> 16;
        const unsigned mid = (c + 1u) >> 1;
        const unsigned i0 = half ? mid : 0u;
        const unsigned i1 = half ? c : mid;
        const unsigned short* kp = keys + (size_t)t * TILE_TOK + (e & 0xFFFFu);
        for (unsigned i = i0; i < i1; ++i) {
            const unsigned loc = kp[i];
            atomicAdd(&h[loc >> 1], (loc & 1u) ? 65536u : 1u);
        }
    }
    __syncthreads();

    // write sweep; emit + p*CPP is ==4 (mod 16) aligned (proven exact R5-R8)
    float* __restrict__ emit = out + BINS;
    float* dst = emit + (size_t)p * CPP;
    if (threadIdx.x < 3)
        dst[threadIdx.x] =
            (float)((h[threadIdx.x >> 1] >> ((threadIdx.x & 1u) * 16)) & 0xFFFFu);
    if (threadIdx.x == 3)
        dst[CPP - 1] = (float)(h[(CPP - 1) >> 1] >> 16);
    float4* dst4 = reinterpret_cast<float4*>(dst + 3);
    for (int u = threadIdx.x; u < (CPP - 4) / 4; u += B2) {   // 7999 float4s
        const unsigned w0 = h[2 * u + 1];
        const unsigned w1 = h[2 * u + 2];
        const unsigned w2 = h[2 * u + 3];
        float4 f;
        f.x = (float)(w0 >> 16);
        f.y = (float)(w1 & 0xFFFFu);
        f.z = (float)(w1 >> 16);
        f.w = (float)(w2 & 0xFFFFu);
        dst4[u] = f;
    }
}

// ---------------- fallback (ws too small) ----------------

__global__ __launch_bounds__(256)
void zero_kernel(uint4* __restrict__ out, int out_quads, int out_size) {
    const uint4 z = {0u, 0u, 0u, 0u};
    const int stride = gridDim.x * blockDim.x;
    for (int q = blockIdx.x * blockDim.x + threadIdx.x; q < out_quads; q += stride)
        out[q] = z;
    if (blockIdx.x == 0 && threadIdx.x < (out_size & 3))
        ((unsigned*)out)[(out_quads << 2) + threadIdx.x] = 0u;
}

__global__ __launch_bounds__(1024)
void count_fallback(const int* __restrict__ words, const int* __restrict__ labels,
                    float* __restrict__ out, int nquads) {
    __shared__ unsigned hist[BINS];
    for (int k = threadIdx.x; k < BINS; k += 1024) hist[k] = 0u;
    __syncthreads();
    float* __restrict__ emit = out + BINS;
    const int stride = gridDim.x * blockDim.x;
    for (int q = blockIdx.x * blockDim.x + threadIdx.x; q < nquads; q += stride) {
        const int i = q << 2;
        const int4 w4 = reinterpret_cast<const int4*>(words)[q];
        const int4 l4 = reinterpret_cast<const int4*>(labels)[q];
        const int j0 = i & (SEQ_LEN - 1);
        int pre = (j0 == 0) ? N_LABELS : labels[i - 1];
        int wv[4] = {w4.x, w4.y, w4.z, w4.w};
        int lv[4] = {l4.x, l4.y, l4.z, l4.w};
        #pragma unroll
        for (int k = 0; k < 4; ++k) {
            const int w = wv[k], lab = lv[k];
            if (w != 0) {
                atomicAdd(&hist[lab * (N_LABELS + 1) + pre], 1u);
                const int we = (w >= N_WORDS) ? 1 : w;
                atomicAdd(&emit[(size_t)we * N_LABELS + lab], 1.0f);
            }
            pre = lab;
        }
    }
    __syncthreads();
    for (int k = threadIdx.x; k < BINS; k += 1024) {
        const unsigned c = hist[k];
        if (c) atomicAdd(&out[k], (float)c);
    }
}

// ---------------- launch ----------------

extern "C" void kernel_launch(void* const* d_in, const int* in_sizes, int n_in,
                              void* d_out, int out_size, void* d_ws, size_t ws_size,
                              hipStream_t stream) {
    const int* words  = (const int*)d_in[0];
    const int* labels = (const int*)d_in[1];
    float* out = (float*)d_out;
    const int n = in_sizes[0];

    const int nquads  = n >> 2;
    const int ntiles  = (nquads + QPT - 1) / QPT;           // 512 at full size
    const int tstride = ((ntiles + 63) / 64) * 64;

    // ws: dir | dirT | keys | part_t
    const size_t dir_bytes  = (size_t)ntiles * P * sizeof(unsigned);
    const size_t dirT_bytes = (size_t)P * tstride * sizeof(unsigned);
    const size_t key_bytes  = (size_t)ntiles * TILE_TOK * sizeof(unsigned short);
    const size_t part_bytes = (size_t)G1 * BINS * sizeof(unsigned);
    const size_t dir_off  = 0;
    const size_t dirT_off = dir_off + ((dir_bytes + 255) & ~size_t(255));
    const size_t key_off  = dirT_off + ((dirT_bytes + 255) & ~size_t(255));
    const size_t part_off = key_off + ((key_bytes + 255) & ~size_t(255));
    const size_t need     = part_off + part_bytes;

    if (ws_size >= need) {
        unsigned*       dir    = (unsigned*)((char*)d_ws + dir_off);
        unsigned*       dirT   = (unsigned*)((char*)d_ws + dirT_off);
        unsigned short* keys   = (unsigned short*)((char*)d_ws + key_off);
        unsigned*       part_t = (unsigned*)((char*)d_ws + part_off);

        phase1<<<G1, B1, 0, stream>>>(words, labels, dir, keys, part_t, n, ntiles);
        dim3 tg((P + 31) / 32, (tstride + 31) / 32);
        transpose_dir<<<tg, dim3(32, 8), 0, stream>>>(dir, dirT, ntiles, tstride);
        phase2<<<P + FIN_BLOCKS, B2, (CPP / 2) * sizeof(unsigned), stream>>>(
            dirT, keys, part_t, out, ntiles, tstride);
    } else {
        const int out_quads = out_size >> 2;
        zero_kernel<<<2048, 256, 0, stream>>>((uint4*)d_out, out_quads, out_size);
        count_fallback<<<512, 1024, 0, stream>>>(words, labels, out, nquads);
    }
}